// Round 1
// baseline (181.848 us; speedup 1.0000x reference)
//
#include <hip/hip_runtime.h>
#include <cfloat>
#include <cmath>

// Loss = l_pair + l_sem + l_att + l_qua
//   l_sem = CE(Yi, y), l_att = CE(Ym, y)           (LAMTA = ROU = 1)
//   l_pair = sum_{i<j} pair(i,j) / (2 B (B-1))
//     D = max(||Fi_i - Fi_j||^2, 0)
//     pair = same_class ? D : max(32 - D, 0)
//   l_qua = 0.1 * mean(-(p log p + (1-p) log(1-p)))  (logs clamped at -100)
//
// pair is symmetric and the diagonal contributes ~0, so
//   sum_{i<j} = (sum over ALL i,j) / 2
// and we only compute upper-triangular 128x128 blocks, weighting
// off-diagonal blocks by 2.
//
// ws layout: [0..2] double accumulators {pair, ce, qua}; offset 256: float sq[B]

#define TILE 128
#define KD   64   // BITS

__global__ void sq_kernel(const float* __restrict__ Fi, float* __restrict__ sq,
                          int B, int BITS) {
    int row = blockIdx.x * blockDim.x + threadIdx.x;
    if (row >= B) return;
    const float4* p = (const float4*)(Fi + (size_t)row * BITS);
    float s = 0.f;
    #pragma unroll
    for (int k = 0; k < KD / 4; ++k) {
        float4 v = p[k];
        s += v.x * v.x + v.y * v.y + v.z * v.z + v.w * v.w;
    }
    sq[row] = s;
}

// One wave per row-task; tasks = rows of Yi then rows of Ym (both coeff 1.0).
__global__ void ce_kernel(const float* __restrict__ Yi, const float* __restrict__ Ym,
                          const int* __restrict__ y, int B, int C,
                          double* __restrict__ ce_acc) {
    int lane  = threadIdx.x & 63;
    int wave  = (blockIdx.x * blockDim.x + threadIdx.x) >> 6;
    int nwave = (gridDim.x * blockDim.x) >> 6;

    float local = 0.f;
    for (int task = wave; task < 2 * B; task += nwave) {
        const float* X = (task < B) ? Yi : Ym;
        int row = (task < B) ? task : task - B;
        const float* xr = X + (size_t)row * C;

        float m = -FLT_MAX;
        for (int c = lane; c < C; c += 64) m = fmaxf(m, xr[c]);
        #pragma unroll
        for (int off = 32; off; off >>= 1) m = fmaxf(m, __shfl_xor(m, off));

        float s = 0.f;
        for (int c = lane; c < C; c += 64) s += expf(xr[c] - m);
        #pragma unroll
        for (int off = 32; off; off >>= 1) s += __shfl_xor(s, off);

        if (lane == 0) {
            float xl = xr[y[row]];
            local += -(xl - m - logf(s));
        }
    }

    __shared__ double part[16];
    int wib = threadIdx.x >> 6;
    if (lane == 0) part[wib] = (double)local;
    __syncthreads();
    if (threadIdx.x == 0) {
        double t = 0.0;
        for (int i = 0; i < (int)(blockDim.x >> 6); ++i) t += part[i];
        atomicAdd(ce_acc, t);
    }
}

__global__ void qua_kernel(const float* __restrict__ Fi, int n,
                           double* __restrict__ acc) {
    int idx    = blockIdx.x * blockDim.x + threadIdx.x;
    int stride = gridDim.x * blockDim.x;
    float local = 0.f;
    for (int i = idx; i < n; i += stride) {
        float p    = Fi[i];
        float lp   = fmaxf(logf(p), -100.f);
        float l1p  = fmaxf(log1pf(-p), -100.f);
        local += -(p * lp + (1.f - p) * l1p);
    }
    #pragma unroll
    for (int off = 32; off; off >>= 1) local += __shfl_xor(local, off);

    __shared__ double part[16];
    int lane = threadIdx.x & 63, wib = threadIdx.x >> 6;
    if (lane == 0) part[wib] = (double)local;
    __syncthreads();
    if (threadIdx.x == 0) {
        double t = 0.0;
        for (int i = 0; i < (int)(blockDim.x >> 6); ++i) t += part[i];
        atomicAdd(acc, t);
    }
}

// 128x128 output tile, 256 threads, 8x8 per thread, K=64 fully staged.
// Upper-triangular block enumeration; off-diagonal weight 2.
__global__ __launch_bounds__(256) void pair_kernel(
    const float* __restrict__ Fi, const float* __restrict__ sq,
    const int* __restrict__ y, int B, double* __restrict__ acc) {

    __shared__ float a_lds[KD][TILE];  // a_lds[k][i] = Fi[i0+i][k]
    __shared__ float b_lds[KD][TILE];  // b_lds[k][j] = Fi[j0+j][k]

    const int NB = B / TILE;
    // decode triangular block index (scalar, <=NB iterations, once per block)
    int rem = blockIdx.x, bi = 0, rowlen = NB;
    while (rem >= rowlen) { rem -= rowlen; rowlen--; bi++; }
    const int bj = bi + rem;
    const int i0 = bi * TILE, j0 = bj * TILE;

    const int t = threadIdx.x;

    // ---- stage: coalesced float4 reads, K-major LDS writes ----
    // Fi tile = 128 rows x 64 cols = 2048 float4; 8 per thread.
    {
        const float4* Fa = (const float4*)(Fi + (size_t)i0 * KD);
        const float4* Fb = (const float4*)(Fi + (size_t)j0 * KD);
        #pragma unroll
        for (int rep = 0; rep < 8; ++rep) {
            int linear = t + rep * 256;
            int row = linear >> 4;       // 0..127
            int q   = linear & 15;       // float4 index within row
            float4 va = Fa[row * 16 + q];
            a_lds[q * 4 + 0][row] = va.x;
            a_lds[q * 4 + 1][row] = va.y;
            a_lds[q * 4 + 2][row] = va.z;
            a_lds[q * 4 + 3][row] = va.w;
            float4 vb = Fb[row * 16 + q];
            b_lds[q * 4 + 0][row] = vb.x;
            b_lds[q * 4 + 1][row] = vb.y;
            b_lds[q * 4 + 2][row] = vb.z;
            b_lds[q * 4 + 3][row] = vb.w;
        }
    }
    __syncthreads();

    // ---- compute: thread (tx,ty) owns i in {4tx..4tx+3, 64+4tx..}, j likewise
    const int tx = t & 15, ty = t >> 4;
    float accr[2][2][4][4];
    #pragma unroll
    for (int p = 0; p < 2; ++p)
        #pragma unroll
        for (int q = 0; q < 2; ++q)
            #pragma unroll
            for (int u = 0; u < 4; ++u)
                #pragma unroll
                for (int v = 0; v < 4; ++v) accr[p][q][u][v] = 0.f;

    #pragma unroll 4
    for (int k = 0; k < KD; ++k) {
        float4 a0 = *(const float4*)&a_lds[k][4 * tx];
        float4 a1 = *(const float4*)&a_lds[k][64 + 4 * tx];
        float4 b0 = *(const float4*)&b_lds[k][4 * ty];
        float4 b1 = *(const float4*)&b_lds[k][64 + 4 * ty];
        float av[2][4] = {{a0.x, a0.y, a0.z, a0.w}, {a1.x, a1.y, a1.z, a1.w}};
        float bv[2][4] = {{b0.x, b0.y, b0.z, b0.w}, {b1.x, b1.y, b1.z, b1.w}};
        #pragma unroll
        for (int p = 0; p < 2; ++p)
            #pragma unroll
            for (int q = 0; q < 2; ++q)
                #pragma unroll
                for (int u = 0; u < 4; ++u)
                    #pragma unroll
                    for (int v = 0; v < 4; ++v)
                        accr[p][q][u][v] = fmaf(av[p][u], bv[q][v], accr[p][q][u][v]);
    }

    // ---- epilogue ----
    const float w = (bi == bj) ? 1.f : 2.f;
    float local = 0.f;
    #pragma unroll
    for (int p = 0; p < 2; ++p) {
        #pragma unroll
        for (int u = 0; u < 4; ++u) {
            int i  = i0 + p * 64 + 4 * tx + u;
            int yi = y[i];
            float si = sq[i];
            #pragma unroll
            for (int q = 0; q < 2; ++q) {
                #pragma unroll
                for (int v = 0; v < 4; ++v) {
                    int j = j0 + q * 64 + 4 * ty + v;
                    float D = si + sq[j] - 2.f * accr[p][q][u][v];
                    D = fmaxf(D, 0.f);
                    float val = (yi == y[j]) ? D : fmaxf(32.f - D, 0.f);
                    local += val;
                }
            }
        }
    }
    local *= w;

    #pragma unroll
    for (int off = 32; off; off >>= 1) local += __shfl_xor(local, off);

    __shared__ double part[4];
    int lane = t & 63, wib = t >> 6;
    if (lane == 0) part[wib] = (double)local;
    __syncthreads();
    if (t == 0) {
        double s = part[0] + part[1] + part[2] + part[3];
        atomicAdd(acc, s);
    }
}

__global__ void finalize_kernel(const double* __restrict__ accs,
                                float* __restrict__ out, int B, int BITS) {
    double l_pair = accs[0] / (4.0 * (double)B * (double)(B - 1));
    double l_ce   = accs[1] / (double)B;             // l_sem + l_att (coeffs 1)
    double l_qua  = 0.1 * accs[2] / ((double)B * (double)BITS);
    out[0] = (float)(l_pair + l_ce + l_qua);
}

extern "C" void kernel_launch(void* const* d_in, const int* in_sizes, int n_in,
                              void* d_out, int out_size, void* d_ws, size_t ws_size,
                              hipStream_t stream) {
    const float* Ym = (const float*)d_in[0];
    const float* Fi = (const float*)d_in[1];
    const float* Yi = (const float*)d_in[2];
    const int*   y  = (const int*)d_in[3];

    const int B    = in_sizes[3];
    const int C    = in_sizes[0] / B;
    const int BITS = in_sizes[1] / B;

    double* accs = (double*)d_ws;
    float*  sq   = (float*)((char*)d_ws + 256);

    hipMemsetAsync(d_ws, 0, 256, stream);

    sq_kernel<<<(B + 255) / 256, 256, 0, stream>>>(Fi, sq, B, BITS);
    ce_kernel<<<256, 256, 0, stream>>>(Yi, Ym, y, B, C, &accs[1]);
    qua_kernel<<<256, 256, 0, stream>>>(Fi, B * BITS, &accs[2]);

    const int NB = B / TILE;
    const int nblk = NB * (NB + 1) / 2;
    pair_kernel<<<nblk, 256, 0, stream>>>(Fi, sq, y, B, &accs[0]);

    finalize_kernel<<<1, 1, 0, stream>>>(accs, (float*)d_out, B, BITS);
}

// Round 3
// 138.832 us; speedup vs baseline: 1.3098x; 1.3098x over previous
//
#include <hip/hip_runtime.h>
#include <cfloat>
#include <cmath>

// Loss = l_pair + l_sem + l_att + l_qua   (see reference)
// pair term via f16 MFMA Gram matrix:
//   Fi rounded to f16 (10 mantissa bits); sq[] computed from the SAME rounded
//   values so D = ||a_h - b_h||^2 exactly (up to fp32 accum) -> errors are
//   symmetric and cancel in the mean.  Upper-triangular 128x128 blocks,
//   off-diagonal weight 2, diagonal weight 1 (i==j contributes 0).
//
// ws layout: [0..2] double accumulators {pair, ce, qua}; offset 256: float sq[B]

#define TILE 128
#define KD   64   // BITS

typedef _Float16 f16x8 __attribute__((ext_vector_type(8)));
typedef float    f32x4 __attribute__((ext_vector_type(4)));

// ---- fused sq (from f16-rounded Fi) + quantization BCE term ----
__global__ void aux_kernel(const float* __restrict__ Fi, float* __restrict__ sq,
                           double* __restrict__ qacc, int B) {
    int row = blockIdx.x * blockDim.x + threadIdx.x;
    float q = 0.f;
    if (row < B) {
        const float4* p = (const float4*)(Fi + (size_t)row * KD);
        float s = 0.f;
        #pragma unroll
        for (int k = 0; k < KD / 4; ++k) {
            float4 v = p[k];
            float xs[4] = {v.x, v.y, v.z, v.w};
            #pragma unroll
            for (int c = 0; c < 4; ++c) {
                float x  = xs[c];
                float hf = (float)(_Float16)x;      // self-consistent with MFMA inputs
                s += hf * hf;
                float lp  = fmaxf(logf(x),    -100.f);
                float l1p = fmaxf(log1pf(-x), -100.f);
                q += -(x * lp + (1.f - x) * l1p);
            }
        }
        sq[row] = s;
    }
    #pragma unroll
    for (int off = 32; off; off >>= 1) q += __shfl_xor(q, off);
    __shared__ double part[4];
    int lane = threadIdx.x & 63, wib = threadIdx.x >> 6;
    if (lane == 0) part[wib] = (double)q;
    __syncthreads();
    if (threadIdx.x == 0)
        atomicAdd(qacc, part[0] + part[1] + part[2] + part[3]);
}

// ---- cross-entropy: one wave per row-task (Yi rows then Ym rows) ----
__global__ void ce_kernel(const float* __restrict__ Yi, const float* __restrict__ Ym,
                          const int* __restrict__ y, int B, int C,
                          double* __restrict__ ce_acc) {
    int lane  = threadIdx.x & 63;
    int wave  = (blockIdx.x * blockDim.x + threadIdx.x) >> 6;
    int nwave = (gridDim.x * blockDim.x) >> 6;

    float local = 0.f;
    for (int task = wave; task < 2 * B; task += nwave) {
        const float* X = (task < B) ? Yi : Ym;
        int row = (task < B) ? task : task - B;
        const float* xr = X + (size_t)row * C;

        // register-cache the row: C=100 -> <=2 elements per lane
        float x0 = xr[lane];                                   // lane < 100 always
        bool  h1 = (lane + 64) < C;
        float x1 = h1 ? xr[lane + 64] : -FLT_MAX;

        float m = fmaxf(x0, x1);
        #pragma unroll
        for (int off = 32; off; off >>= 1) m = fmaxf(m, __shfl_xor(m, off));

        float s = expf(x0 - m) + (h1 ? expf(x1 - m) : 0.f);
        #pragma unroll
        for (int off = 32; off; off >>= 1) s += __shfl_xor(s, off);

        if (lane == 0) {
            float xl = xr[y[row]];
            local += -(xl - m - logf(s));
        }
    }

    __shared__ double part[16];
    int wib = threadIdx.x >> 6;
    if (lane == 0) part[wib] = (double)local;
    __syncthreads();
    if (threadIdx.x == 0) {
        double t = 0.0;
        for (int i = 0; i < (int)(blockDim.x >> 6); ++i) t += part[i];
        atomicAdd(ce_acc, t);
    }
}

// ---- pair term: 128x128 tile, 4 waves (2x2), each wave 64x64 via 4x4
//      fragments of v_mfma_f32_16x16x32_f16.  K=64 = 2 k-steps.
//      Panels in LDS as row-major [128][64] f16 with T2 XOR swizzle
//      (byte ^= (row&7)<<4) on both write and read -> conflict-free. ----
__global__ __launch_bounds__(256) void pair_kernel(
    const float* __restrict__ Fi, const float* __restrict__ sq,
    const int* __restrict__ y, int B, double* __restrict__ acc) {

    __shared__ __align__(16) _Float16 aP[TILE * KD];
    __shared__ __align__(16) _Float16 bP[TILE * KD];
    __shared__ int   yi_s[TILE], yj_s[TILE];
    __shared__ float sqi_s[TILE], sqj_s[TILE];

    const int NB = B / TILE;
    int rem = blockIdx.x, bi = 0, rowlen = NB;            // triangular decode
    while (rem >= rowlen) { rem -= rowlen; rowlen--; bi++; }
    const int bj = bi + rem;
    const int i0 = bi * TILE, j0 = bj * TILE;

    const int t = threadIdx.x;

    // stage y / sq slices
    if (t < TILE) { yi_s[t] = y[i0 + t]; sqi_s[t] = sq[i0 + t]; }
    else { int u = t - TILE; yj_s[u] = y[j0 + u]; sqj_s[u] = sq[j0 + u]; }

    // stage panels: f32 global -> f16 LDS, swizzled 8B writes
    {
        const float4* Fa = (const float4*)(Fi + (size_t)i0 * KD);
        const float4* Fb = (const float4*)(Fi + (size_t)j0 * KD);
        #pragma unroll
        for (int rep = 0; rep < 8; ++rep) {
            int linear = rep * 256 + t;
            int row = linear >> 4;            // 0..127
            int q   = linear & 15;            // float4 index in row
            uint off = (uint)(row * 128 + q * 8);
            off ^= (uint)((row & 7) << 4);
            union { _Float16 h[4]; uint2 u2; } cv;
            float4 va = Fa[row * 16 + q];
            cv.h[0] = (_Float16)va.x; cv.h[1] = (_Float16)va.y;
            cv.h[2] = (_Float16)va.z; cv.h[3] = (_Float16)va.w;
            *(uint2*)((char*)aP + off) = cv.u2;
            float4 vb = Fb[row * 16 + q];
            cv.h[0] = (_Float16)vb.x; cv.h[1] = (_Float16)vb.y;
            cv.h[2] = (_Float16)vb.z; cv.h[3] = (_Float16)vb.w;
            *(uint2*)((char*)bP + off) = cv.u2;
        }
    }
    __syncthreads();

    const int lane = t & 63, wave = t >> 6;
    const int wm = wave >> 1, wn = wave & 1;      // 2x2 waves over 128x128
    const int r16 = lane & 15, g = lane >> 4;

    f32x4 accf[4][4];
    #pragma unroll
    for (int a = 0; a < 4; ++a)
        #pragma unroll
        for (int b = 0; b < 4; ++b) accf[a][b] = (f32x4){0.f, 0.f, 0.f, 0.f};

    #pragma unroll
    for (int ks = 0; ks < 2; ++ks) {
        f16x8 af[4], bf[4];
        #pragma unroll
        for (int mf = 0; mf < 4; ++mf) {
            int row = wm * 64 + mf * 16 + r16;
            uint off = (uint)(row * 128 + ks * 64 + g * 16);
            off ^= (uint)((row & 7) << 4);
            af[mf] = *(const f16x8*)((const char*)aP + off);
        }
        #pragma unroll
        for (int nf = 0; nf < 4; ++nf) {
            int row = wn * 64 + nf * 16 + r16;
            uint off = (uint)(row * 128 + ks * 64 + g * 16);
            off ^= (uint)((row & 7) << 4);
            bf[nf] = *(const f16x8*)((const char*)bP + off);
        }
        #pragma unroll
        for (int mf = 0; mf < 4; ++mf)
            #pragma unroll
            for (int nf = 0; nf < 4; ++nf)
                accf[mf][nf] = __builtin_amdgcn_mfma_f32_16x16x32_f16(
                    af[mf], bf[nf], accf[mf][nf], 0, 0, 0);
    }

    // epilogue: C[m][n] with m=(lane>>4)*4+reg, n=lane&15 (HW-verified layout)
    const float w = (bi == bj) ? 1.f : 2.f;
    float local = 0.f;
    #pragma unroll
    for (int nf = 0; nf < 4; ++nf) {
        int jl = wn * 64 + nf * 16 + r16;
        int   yj = yj_s[jl];
        float sj = sqj_s[jl];
        #pragma unroll
        for (int mf = 0; mf < 4; ++mf) {
            #pragma unroll
            for (int r = 0; r < 4; ++r) {
                int il = wm * 64 + mf * 16 + g * 4 + r;
                float D = sqi_s[il] + sj - 2.f * accf[mf][nf][r];
                D = fmaxf(D, 0.f);
                float val = (yi_s[il] == yj) ? D : fmaxf(32.f - D, 0.f);
                local += val;
            }
        }
    }
    local *= w;

    #pragma unroll
    for (int off = 32; off; off >>= 1) local += __shfl_xor(local, off);

    __shared__ double part[4];
    if (lane == 0) part[wave] = (double)local;
    __syncthreads();
    if (t == 0) atomicAdd(acc, part[0] + part[1] + part[2] + part[3]);
}

__global__ void finalize_kernel(const double* __restrict__ accs,
                                float* __restrict__ out, int B, int BITS) {
    double l_pair = accs[0] / (4.0 * (double)B * (double)(B - 1));
    double l_ce   = accs[1] / (double)B;             // l_sem + l_att (coeffs 1)
    double l_qua  = 0.1 * accs[2] / ((double)B * (double)BITS);
    out[0] = (float)(l_pair + l_ce + l_qua);
}

extern "C" void kernel_launch(void* const* d_in, const int* in_sizes, int n_in,
                              void* d_out, int out_size, void* d_ws, size_t ws_size,
                              hipStream_t stream) {
    const float* Ym = (const float*)d_in[0];
    const float* Fi = (const float*)d_in[1];
    const float* Yi = (const float*)d_in[2];
    const int*   y  = (const int*)d_in[3];

    const int B    = in_sizes[3];
    const int C    = in_sizes[0] / B;
    const int BITS = in_sizes[1] / B;

    double* accs = (double*)d_ws;
    float*  sq   = (float*)((char*)d_ws + 256);

    hipMemsetAsync(d_ws, 0, 256, stream);

    aux_kernel<<<(B + 255) / 256, 256, 0, stream>>>(Fi, sq, &accs[2], B);
    ce_kernel<<<256, 256, 0, stream>>>(Yi, Ym, y, B, C, &accs[1]);

    const int NB = B / TILE;
    const int nblk = NB * (NB + 1) / 2;
    pair_kernel<<<nblk, 256, 0, stream>>>(Fi, sq, y, B, &accs[0]);

    finalize_kernel<<<1, 1, 0, stream>>>(accs, (float*)d_out, B, BITS);
}

// Round 5
// 108.755 us; speedup vs baseline: 1.6721x; 1.2766x over previous
//
#include <hip/hip_runtime.h>
#include <cfloat>
#include <cmath>

// Loss = l_pair + l_sem + l_att + l_qua   (see reference)
//
// Single fused kernel; block role by blockIdx:
//   [0, nblk)            pair tiles: 128x128 upper-tri blocks, f16 MFMA Gram,
//                        sq[] derived in-block from the staged f16 panels.
//   [nblk, nblk+NCE)     cross-entropy over Yi rows then Ym rows (wave/row).
//   [nblk+NCE, +NQ)      quantization BCE, grid-stride float4, exact f32.
// Then a 1-thread finalize kernel combines the 3 double accumulators.
//
// ws layout: [0..2] double accumulators {pair, ce, qua}

#define TILE 128
#define KD   64   // BITS
#define NCE  512
#define NQ   128

typedef _Float16 f16x8 __attribute__((ext_vector_type(8)));
typedef _Float16 f16x4 __attribute__((ext_vector_type(4)));
typedef float    f32x4 __attribute__((ext_vector_type(4)));

__global__ __launch_bounds__(256) void fused_kernel(
    const float* __restrict__ Fi, const float* __restrict__ Yi,
    const float* __restrict__ Ym, const int* __restrict__ y,
    int B, int C, int nblk, double* __restrict__ accs) {

    __shared__ __align__(16) _Float16 aP[TILE * KD];
    __shared__ __align__(16) _Float16 bP[TILE * KD];
    __shared__ int   yi_s[TILE], yj_s[TILE];
    __shared__ float sqi_s[TILE], sqj_s[TILE];
    __shared__ double part[4];

    const int t    = threadIdx.x;
    const int lane = t & 63;
    const int wib  = t >> 6;

    // ================= CE role =================
    if ((int)blockIdx.x >= nblk && (int)blockIdx.x < nblk + NCE) {
        int wave  = ((int)blockIdx.x - nblk) * 4 + wib;
        int nwave = NCE * 4;
        float local = 0.f;
        for (int task = wave; task < 2 * B; task += nwave) {
            const float* X = (task < B) ? Yi : Ym;
            int row = (task < B) ? task : task - B;
            const float* xr = X + (size_t)row * C;

            float x0 = (lane < C) ? xr[lane] : -FLT_MAX;
            bool  h1 = (lane + 64) < C;
            float x1 = h1 ? xr[lane + 64] : -FLT_MAX;

            float m = fmaxf(x0, x1);
            #pragma unroll
            for (int off = 32; off; off >>= 1) m = fmaxf(m, __shfl_xor(m, off));

            float s = ((lane < C) ? expf(x0 - m) : 0.f) + (h1 ? expf(x1 - m) : 0.f);
            #pragma unroll
            for (int off = 32; off; off >>= 1) s += __shfl_xor(s, off);

            if (lane == 0) {
                float xl = xr[y[row]];
                local += -(xl - m - logf(s));
            }
        }
        if (lane == 0) part[wib] = (double)local;
        __syncthreads();
        if (t == 0) atomicAdd(&accs[1], part[0] + part[1] + part[2] + part[3]);
        return;
    }

    // ================= qua role =================
    if ((int)blockIdx.x >= nblk + NCE) {
        int base = ((int)blockIdx.x - nblk - NCE) * 256 + t;
        int n4   = (B * KD) >> 2;
        float q = 0.f;
        const float4* Fi4 = (const float4*)Fi;
        for (int i = base; i < n4; i += NQ * 256) {
            float4 v = Fi4[i];
            float xs[4] = {v.x, v.y, v.z, v.w};
            #pragma unroll
            for (int c = 0; c < 4; ++c) {
                float x   = xs[c];
                float lp  = fmaxf(logf(x),    -100.f);
                float l1p = fmaxf(log1pf(-x), -100.f);
                q += -(x * lp + (1.f - x) * l1p);
            }
        }
        #pragma unroll
        for (int off = 32; off; off >>= 1) q += __shfl_xor(q, off);
        if (lane == 0) part[wib] = (double)q;
        __syncthreads();
        if (t == 0) atomicAdd(&accs[2], part[0] + part[1] + part[2] + part[3]);
        return;
    }

    // ================= pair role =================
    const int NB = B / TILE;
    int rem = blockIdx.x, bi = 0, rowlen = NB;            // triangular decode
    while (rem >= rowlen) { rem -= rowlen; rowlen--; bi++; }
    const int bj = bi + rem;
    const int i0 = bi * TILE, j0 = bj * TILE;

    // stage y slices
    if (t < TILE) yi_s[t] = y[i0 + t];
    else          yj_s[t - TILE] = y[j0 + t - TILE];

    // stage panels: f32 global -> f16 LDS, swizzled 8B writes
    {
        const float4* Fa = (const float4*)(Fi + (size_t)i0 * KD);
        const float4* Fb = (const float4*)(Fi + (size_t)j0 * KD);
        #pragma unroll
        for (int rep = 0; rep < 8; ++rep) {
            int linear = rep * 256 + t;
            int row = linear >> 4;            // 0..127
            int q   = linear & 15;            // float4 index in row
            uint off = (uint)(row * 128 + q * 8);
            off ^= (uint)((row & 7) << 4);
            union { _Float16 h[4]; uint2 u2; } cv;
            float4 va = Fa[row * 16 + q];
            cv.h[0] = (_Float16)va.x; cv.h[1] = (_Float16)va.y;
            cv.h[2] = (_Float16)va.z; cv.h[3] = (_Float16)va.w;
            *(uint2*)((char*)aP + off) = cv.u2;
            float4 vb = Fb[row * 16 + q];
            cv.h[0] = (_Float16)vb.x; cv.h[1] = (_Float16)vb.y;
            cv.h[2] = (_Float16)vb.z; cv.h[3] = (_Float16)vb.w;
            *(uint2*)((char*)bP + off) = cv.u2;
        }
    }
    __syncthreads();

    // sq from the staged f16 panels (self-consistent with MFMA inputs)
    {
        int row = t & 127;
        const _Float16* P = (t >= 128) ? bP : aP;
        float s = 0.f;
        #pragma unroll
        for (int kq = 0; kq < 16; ++kq) {
            uint off = (uint)(row * 128 + kq * 8);
            off ^= (uint)((row & 7) << 4);
            f16x4 h = *(const f16x4*)((const char*)P + off);
            #pragma unroll
            for (int c = 0; c < 4; ++c) {
                float hf = (float)h[c];
                s += hf * hf;
            }
        }
        if (t >= 128) sqj_s[row] = s; else sqi_s[row] = s;
    }

    const int wave = wib;
    const int wm = wave >> 1, wn = wave & 1;      // 2x2 waves over 128x128
    const int r16 = lane & 15, g = lane >> 4;

    f32x4 accf[4][4];
    #pragma unroll
    for (int a = 0; a < 4; ++a)
        #pragma unroll
        for (int b = 0; b < 4; ++b) accf[a][b] = (f32x4){0.f, 0.f, 0.f, 0.f};

    #pragma unroll
    for (int ks = 0; ks < 2; ++ks) {
        f16x8 af[4], bf[4];
        #pragma unroll
        for (int mf = 0; mf < 4; ++mf) {
            int row = wm * 64 + mf * 16 + r16;
            uint off = (uint)(row * 128 + ks * 64 + g * 16);
            off ^= (uint)((row & 7) << 4);
            af[mf] = *(const f16x8*)((const char*)aP + off);
        }
        #pragma unroll
        for (int nf = 0; nf < 4; ++nf) {
            int row = wn * 64 + nf * 16 + r16;
            uint off = (uint)(row * 128 + ks * 64 + g * 16);
            off ^= (uint)((row & 7) << 4);
            bf[nf] = *(const f16x8*)((const char*)bP + off);
        }
        #pragma unroll
        for (int mf = 0; mf < 4; ++mf)
            #pragma unroll
            for (int nf = 0; nf < 4; ++nf)
                accf[mf][nf] = __builtin_amdgcn_mfma_f32_16x16x32_f16(
                    af[mf], bf[nf], accf[mf][nf], 0, 0, 0);
    }
    __syncthreads();   // sq writes visible before epilogue reads

    // epilogue: C[m][n] with m=(lane>>4)*4+reg, n=lane&15 (HW-verified layout)
    const float w = (bi == bj) ? 1.f : 2.f;
    float local = 0.f;
    #pragma unroll
    for (int nf = 0; nf < 4; ++nf) {
        int jl = wn * 64 + nf * 16 + r16;
        int   yj = yj_s[jl];
        float sj = sqj_s[jl];
        #pragma unroll
        for (int mf = 0; mf < 4; ++mf) {
            #pragma unroll
            for (int r = 0; r < 4; ++r) {
                int il = wm * 64 + mf * 16 + g * 4 + r;
                float D = sqi_s[il] + sj - 2.f * accf[mf][nf][r];
                D = fmaxf(D, 0.f);
                float val = (yi_s[il] == yj) ? D : fmaxf(32.f - D, 0.f);
                local += val;
            }
        }
    }
    local *= w;

    #pragma unroll
    for (int off = 32; off; off >>= 1) local += __shfl_xor(local, off);

    if (lane == 0) part[wave] = (double)local;
    __syncthreads();
    if (t == 0) atomicAdd(&accs[0], part[0] + part[1] + part[2] + part[3]);
}

__global__ void finalize_kernel(const double* __restrict__ accs,
                                float* __restrict__ out, int B, int BITS) {
    double l_pair = accs[0] / (4.0 * (double)B * (double)(B - 1));
    double l_ce   = accs[1] / (double)B;             // l_sem + l_att (coeffs 1)
    double l_qua  = 0.1 * accs[2] / ((double)B * (double)BITS);
    out[0] = (float)(l_pair + l_ce + l_qua);
}

extern "C" void kernel_launch(void* const* d_in, const int* in_sizes, int n_in,
                              void* d_out, int out_size, void* d_ws, size_t ws_size,
                              hipStream_t stream) {
    const float* Ym = (const float*)d_in[0];
    const float* Fi = (const float*)d_in[1];
    const float* Yi = (const float*)d_in[2];
    const int*   y  = (const int*)d_in[3];

    const int B    = in_sizes[3];
    const int C    = in_sizes[0] / B;
    const int BITS = in_sizes[1] / B;   // == KD
    (void)BITS;

    double* accs = (double*)d_ws;
    hipMemsetAsync(d_ws, 0, 256, stream);

    const int NB   = B / TILE;
    const int nblk = NB * (NB + 1) / 2;

    fused_kernel<<<nblk + NCE + NQ, 256, 0, stream>>>(Fi, Yi, Ym, y, B, C, nblk, accs);
    finalize_kernel<<<1, 1, 0, stream>>>(accs, (float*)d_out, B, BITS);
}